// Round 3
// baseline (279.747 us; speedup 1.0000x reference)
//
#include <hip/hip_runtime.h>
#include <hip/hip_bf16.h>

// ---------------------------------------------------------------------------
// WindowAttention: B=32 RES=56 C=128 HEADS=4 HD=32 WS=7 NW=8 NQ=64 WA=49
// TOPK=64 -> 128 keys/window (64 gathered from full-res, 64 from x1-level).
// I/O dtype: FLOAT32 (per reference setup_inputs; threshold arithmetic shows
// no bf16 floor was applied). Internally: bf16 MFMA (2% threshold, ~2x margin).
// Buffer plan:
//   d_out (fp32, 51.4MB): q_win (windowed q) -> overwritten in place by attn
//   output (channel-disjoint alias) -> k_proj in-place (row-disjoint blocks).
//   d_ws 56.1MB: k0,v0,k1,v1 (bf16) + rpb (fp32).
// ---------------------------------------------------------------------------

typedef __bf16 bf16_t;
typedef __bf16 bf16x8 __attribute__((ext_vector_type(8)));
typedef float f32x4 __attribute__((ext_vector_type(4)));

static __device__ __forceinline__ f32x4 mfma_bf16(bf16x8 a, bf16x8 b, f32x4 c) {
  return __builtin_amdgcn_mfma_f32_16x16x32_bf16(a, b, c, 0, 0, 0);
}

// load 8 consecutive fp32 and round to bf16x8
static __device__ __forceinline__ bf16x8 cvt8(const float* __restrict__ p) {
  float4 a = *(const float4*)p;
  float4 b = *(const float4*)(p + 4);
  bf16x8 r;
  r[0] = (bf16_t)a.x; r[1] = (bf16_t)a.y; r[2] = (bf16_t)a.z; r[3] = (bf16_t)a.w;
  r[4] = (bf16_t)b.x; r[5] = (bf16_t)b.y; r[6] = (bf16_t)b.z; r[7] = (bf16_t)b.w;
  return r;
}

#define NB 32
#define RES 56
#define CH 128
#define HD 32
#define NW 8
#define NQ 64
#define WA 49
#define X0_ROWS (NB * RES * RES)       // 100352
#define X1_ROWS (NB * NQ)              // 2048

// ---------------------------------------------------------------------------
// K1: qkv = [x0;x1] @ qkv_w.T + qkv_b. q -> fp32 windowed into d_out;
// k/v -> bf16 k0/v0 (x0 rows) and k1/v1 (x1 rows).
// grid (1600, 3) x 256. 64-row x 128-col tile, K=128.
// ---------------------------------------------------------------------------
__global__ __launch_bounds__(256) void k_qkv(
    const float* __restrict__ x0, const float* __restrict__ x1,
    const float* __restrict__ w, const float* __restrict__ bias,
    float* __restrict__ qwin, bf16_t* __restrict__ k0, bf16_t* __restrict__ v0,
    bf16_t* __restrict__ k1, bf16_t* __restrict__ v1) {
  __shared__ __align__(16) bf16_t Asm[64][136];
  __shared__ __align__(16) bf16_t Bsm[128][136];
  const int rb = blockIdx.x;           // 0..1599 (rows 1568.. are x1)
  const int cb = blockIdx.y;           // 0:q 1:k 2:v
  const int tid = threadIdx.x;
  const size_t row0 = (size_t)rb * 64;

  const float* src = (rb < 1568) ? (x0 + row0 * CH)
                                 : (x1 + (row0 - X0_ROWS) * CH);
#pragma unroll
  for (int i = 0; i < 4; ++i) {        // A: 64x128 = 1024 groups of 8
    int uid = tid + 256 * i;
    int r = uid >> 4, cs = uid & 15;
    *(bf16x8*)&Asm[r][cs * 8] = cvt8(src + (size_t)r * CH + cs * 8);
  }
  const float* wsrc = w + (size_t)cb * 128 * CH;
#pragma unroll
  for (int i = 0; i < 8; ++i) {        // B: 128x128 = 2048 groups of 8
    int uid = tid + 256 * i;
    int r = uid >> 4, cs = uid & 15;
    *(bf16x8*)&Bsm[r][cs * 8] = cvt8(wsrc + (size_t)r * CH + cs * 8);
  }
  __syncthreads();

  const int wid = tid >> 6, l = tid & 63;
  const int lr = l & 15, lkg = l >> 4, lk = lkg * 8;
  f32x4 zero = {0.f, 0.f, 0.f, 0.f};
  f32x4 acc[8];
#pragma unroll
  for (int nt = 0; nt < 8; ++nt) acc[nt] = zero;
#pragma unroll
  for (int ks = 0; ks < 4; ++ks) {
    bf16x8 a = *(const bf16x8*)&Asm[wid * 16 + lr][ks * 32 + lk];
#pragma unroll
    for (int nt = 0; nt < 8; ++nt) {
      bf16x8 b = *(const bf16x8*)&Bsm[nt * 16 + lr][ks * 32 + lk];
      acc[nt] = mfma_bf16(a, b, acc[nt]);
    }
  }
  // epilogue: bias + scatter
#pragma unroll
  for (int nt = 0; nt < 8; ++nt) {
    int n = nt * 16 + lr;
    float bs = bias[cb * 128 + n];
#pragma unroll
    for (int r4 = 0; r4 < 4; ++r4) {
      size_t g = row0 + (size_t)(wid * 16 + lkg * 4 + r4);
      float fv = acc[nt][r4] + bs;
      if (g < (size_t)X0_ROWS) {
        size_t b_ = g / 3136, pix = g % 3136;
        int rr = (int)(pix / RES), cc = (int)(pix % RES);
        if (cb == 0) {
          int qidx = (rr / 7) * NW + (cc / 7);
          int nidx = (rr % 7) * 7 + (cc % 7);
          qwin[((b_ * NQ + qidx) * WA + nidx) * CH + n] = fv;   // fp32 q
        } else if (cb == 1) {
          k0[g * CH + n] = (bf16_t)fv;
        } else {
          v0[g * CH + n] = (bf16_t)fv;
        }
      } else {
        size_t i1 = g - X0_ROWS;
        if (cb == 1) k1[i1 * CH + n] = (bf16_t)fv;
        else if (cb == 2) v1[i1 * CH + n] = (bf16_t)fv;
        // cb==0 (q of x1) unused by the reference
      }
    }
  }
}

// ---------------------------------------------------------------------------
// K2: rpb MLP -> rpb[((q*4+h)*49+n)*128+m], fp32. grid 1568 x 256. All fp32.
// ---------------------------------------------------------------------------
__global__ __launch_bounds__(256) void k_rpb(
    const float* __restrict__ c0, const float* __restrict__ c1,
    const float* __restrict__ w10, const float* __restrict__ b10,
    const float* __restrict__ w20, const float* __restrict__ b20,
    const float* __restrict__ w11, const float* __restrict__ b11,
    const float* __restrict__ w21, const float* __restrict__ b21,
    float* __restrict__ rpb) {
  __shared__ float w1s[2][32][2], b1s[2][32], w2s[2][4][32], b2s[2][4];
  const int tid = threadIdx.x;
  if (tid < 64) {
    int s = tid >> 5, j = tid & 31;
    const float* w1p = s ? w11 : w10;
    const float* b1p = s ? b11 : b10;
    w1s[s][j][0] = w1p[j * 2];
    w1s[s][j][1] = w1p[j * 2 + 1];
    b1s[s][j] = b1p[j];
  }
  {
    int s = tid >> 7, rem = tid & 127, h = rem >> 5, j = rem & 31;
    w2s[s][h][j] = s ? w21[h * 32 + j] : w20[h * 32 + j];
  }
  if (tid < 8) {
    int s = tid >> 2, h = tid & 3;
    b2s[s][h] = s ? b21[h] : b20[h];
  }
  __syncthreads();

  int L = blockIdx.x * 256 + tid;      // < 64*49*128 = 401408
  int m = L & 127;
  int n = (L >> 7) % WA;
  int qi = L / (128 * WA);
  int s = m >> 6, mi = m & 63;
  const float* cp = (s ? c1 : c0) + (((size_t)qi * WA + n) * 64 + mi) * 2;
  float cx = cp[0], cy = cp[1];
  float a0 = 0.f, a1 = 0.f, a2 = 0.f, a3 = 0.f;
#pragma unroll
  for (int j = 0; j < 32; ++j) {
    float h = fmaxf(w1s[s][j][0] * cx + w1s[s][j][1] * cy + b1s[s][j], 0.f);
    a0 += w2s[s][0][j] * h;
    a1 += w2s[s][1][j] * h;
    a2 += w2s[s][2][j] * h;
    a3 += w2s[s][3][j] * h;
  }
  size_t base = ((size_t)qi * 4 * WA + n) * 128 + m;  // head stride = 49*128
  rpb[base] = a0 + b2s[s][0];
  rpb[base + (size_t)WA * 128] = a1 + b2s[s][1];
  rpb[base + (size_t)2 * WA * 128] = a2 + b2s[s][2];
  rpb[base + (size_t)3 * WA * 128] = a3 + b2s[s][3];
}

// ---------------------------------------------------------------------------
// K3: attention. block = (b, window qi, head-pair hp). 256 thr (4 waves).
// Gather Kt[128key][64ch] and Vt[64ch][128key] (bf16) into LDS.
// Per head: QK^T -> softmax(+scale+rpb) -> PV -> /rowsum -> fp32 store.
// qwin/attn_out alias (fp32, NO restrict): block reads q channel-slice
// [hp*64+lh*32, +32) strictly before writing it; rows clamped inside window.
// ---------------------------------------------------------------------------
__global__ __launch_bounds__(256) void k_attn(
    const float* qwin,                  // aliases attn_out — no restrict!
    const bf16_t* __restrict__ k0, const bf16_t* __restrict__ v0,
    const bf16_t* __restrict__ k1, const bf16_t* __restrict__ v1,
    const int* __restrict__ idx0, const int* __restrict__ idx1,
    const float* __restrict__ rpb,
    float* attn_out) {                  // aliases qwin — no restrict!
  __shared__ __align__(16) bf16_t Kt[128][72];   // [key][ch-in-pair], pad 8
  __shared__ __align__(16) bf16_t Vt[64][136];   // [ch-in-pair][key], pad 8
  __shared__ __align__(16) bf16_t Sm[64][136];   // scores -> P (per head)
  __shared__ float rowsum[64];

  const int bid = blockIdx.x;          // 4096 = 32*64*2
  const int hp = bid & 1;
  const int qi = (bid >> 1) & 63;
  const int b = bid >> 7;
  const int tid = threadIdx.x;

  // gather K/V rows (channel slice hp*64..hp*64+63)
#pragma unroll
  for (int i = 0; i < 4; ++i) {
    int uid = tid + 256 * i;           // 0..1023
    int key = uid >> 3, seg = uid & 7;
    size_t srcrow;
    const bf16_t *kbase, *vbase;
    if (key < 64) {
      srcrow = (size_t)b * 3136 + idx0[qi * 64 + key];
      kbase = k0; vbase = v0;
    } else {
      srcrow = (size_t)b * 64 + idx1[qi * 64 + key - 64];
      kbase = k1; vbase = v1;
    }
    size_t off = srcrow * CH + hp * 64 + seg * 8;
    *(uint4*)&Kt[key][seg * 8] = *(const uint4*)(kbase + off);
    union { uint4 u; bf16_t h[8]; } cv;
    cv.u = *(const uint4*)(vbase + off);
#pragma unroll
    for (int e0 = 0; e0 < 8; ++e0) {   // rotate to spread LDS banks
      int e = (e0 + key) & 7;
      Vt[seg * 8 + e][key] = cv.h[e];
    }
  }
  __syncthreads();

  const int wid = tid >> 6, l = tid & 63;
  const int lr = l & 15, lkg = l >> 4, lk = lkg * 8;
  const size_t bq49 = ((size_t)b * NQ + qi) * WA;
  const float scale = 0.17677669529663687f;  // 32^-0.5
  f32x4 zero = {0.f, 0.f, 0.f, 0.f};

  // clamped q row: rows 49..63 duplicate row 48 (results discarded) so we
  // never touch another block's rows.
  int qr = wid * 16 + lr;
  if (qr > WA - 1) qr = WA - 1;

  for (int lh = 0; lh < 2; ++lh) {
    const int hh = hp * 2 + lh;
    // ---- QK^T : wave wid handles query rows wid*16..wid*16+15
    bf16x8 a = cvt8(qwin + (bq49 + qr) * CH + hh * 32 + lk);
    f32x4 acc[8];
#pragma unroll
    for (int nt = 0; nt < 8; ++nt) {
      bf16x8 bfr = *(const bf16x8*)&Kt[nt * 16 + lr][lh * 32 + lk];
      acc[nt] = mfma_bf16(a, bfr, zero);
    }
#pragma unroll
    for (int nt = 0; nt < 8; ++nt) {
#pragma unroll
      for (int r4 = 0; r4 < 4; ++r4) {
        Sm[wid * 16 + lkg * 4 + r4][nt * 16 + lr] = (bf16_t)(acc[nt][r4] * scale);
      }
    }
    __syncthreads();

    // ---- softmax: 4 threads per row, 32 cols each
    {
      int rown = tid >> 2, quad = tid & 3;
      if (rown < WA) {
        const float* rp = rpb + (((size_t)qi * 4 + hh) * WA + rown) * 128 + quad * 32;
        float vals[32];
        float mx = -1e30f;
#pragma unroll
        for (int j = 0; j < 32; ++j) {
          float sv = (float)Sm[rown][quad * 32 + j] + rp[j];
          vals[j] = sv;
          mx = fmaxf(mx, sv);
        }
        mx = fmaxf(mx, __shfl_xor(mx, 1));
        mx = fmaxf(mx, __shfl_xor(mx, 2));
        float sum = 0.f;
#pragma unroll
        for (int j = 0; j < 32; ++j) {
          float e = __expf(vals[j] - mx);
          sum += e;
          Sm[rown][quad * 32 + j] = (bf16_t)e;   // unnormalized P in-place
        }
        sum += __shfl_xor(sum, 1);
        sum += __shfl_xor(sum, 2);
        if (quad == 0) rowsum[rown] = sum;
      }
    }
    __syncthreads();

    // ---- PV : O[n][ch] = sum_m P[n][m] V[m][ch]
    f32x4 oacc[2];
    oacc[0] = zero; oacc[1] = zero;
#pragma unroll
    for (int ks = 0; ks < 4; ++ks) {
      bf16x8 pa = *(const bf16x8*)&Sm[wid * 16 + lr][ks * 32 + lk];
#pragma unroll
      for (int nt2 = 0; nt2 < 2; ++nt2) {
        bf16x8 vb = *(const bf16x8*)&Vt[lh * 32 + nt2 * 16 + lr][ks * 32 + lk];
        oacc[nt2] = mfma_bf16(pa, vb, oacc[nt2]);
      }
    }
#pragma unroll
    for (int nt2 = 0; nt2 < 2; ++nt2) {
#pragma unroll
      for (int r4 = 0; r4 < 4; ++r4) {
        int rown2 = wid * 16 + lkg * 4 + r4;
        if (rown2 < WA) {
          float ov = oacc[nt2][r4] / rowsum[rown2];
          attn_out[(bq49 + rown2) * CH + hh * 32 + nt2 * 16 + lr] = ov;  // fp32
        }
      }
    }
    __syncthreads();   // Sm reused by next head
  }
}

// ---------------------------------------------------------------------------
// K4: out = attn @ proj_w.T + proj_b, IN PLACE on d_out (fp32 -> fp32).
// Safe: each block stages its own 64 rows into LDS before the barrier, then
// overwrites exactly those rows; blocks touch disjoint rows.
// ---------------------------------------------------------------------------
__global__ __launch_bounds__(256) void k_proj(
    const float* attn,                  // aliases out — no restrict!
    const float* __restrict__ pw, const float* __restrict__ pb,
    float* out) {
  __shared__ __align__(16) bf16_t Asm[64][136];
  __shared__ __align__(16) bf16_t Bsm[128][136];
  const int rb = blockIdx.x;
  const int tid = threadIdx.x;
  const size_t row0 = (size_t)rb * 64;
#pragma unroll
  for (int i = 0; i < 4; ++i) {
    int uid = tid + 256 * i;
    int r = uid >> 4, cs = uid & 15;
    *(bf16x8*)&Asm[r][cs * 8] = cvt8(attn + (row0 + r) * CH + cs * 8);
  }
#pragma unroll
  for (int i = 0; i < 8; ++i) {
    int uid = tid + 256 * i;
    int r = uid >> 4, cs = uid & 15;
    *(bf16x8*)&Bsm[r][cs * 8] = cvt8(pw + (size_t)r * CH + cs * 8);
  }
  __syncthreads();

  const int wid = tid >> 6, l = tid & 63;
  const int lr = l & 15, lkg = l >> 4, lk = lkg * 8;
  f32x4 zero = {0.f, 0.f, 0.f, 0.f};
  f32x4 acc[8];
#pragma unroll
  for (int nt = 0; nt < 8; ++nt) acc[nt] = zero;
#pragma unroll
  for (int ks = 0; ks < 4; ++ks) {
    bf16x8 a = *(const bf16x8*)&Asm[wid * 16 + lr][ks * 32 + lk];
#pragma unroll
    for (int nt = 0; nt < 8; ++nt) {
      bf16x8 b = *(const bf16x8*)&Bsm[nt * 16 + lr][ks * 32 + lk];
      acc[nt] = mfma_bf16(a, b, acc[nt]);
    }
  }
#pragma unroll
  for (int nt = 0; nt < 8; ++nt) {
    int n = nt * 16 + lr;
    float bs = pb[n];
#pragma unroll
    for (int r4 = 0; r4 < 4; ++r4) {
      size_t g = row0 + (size_t)(wid * 16 + lkg * 4 + r4);
      out[g * CH + n] = acc[nt][r4] + bs;
    }
  }
}

// ---------------------------------------------------------------------------
// launch
// ---------------------------------------------------------------------------
extern "C" void kernel_launch(void* const* d_in, const int* in_sizes, int n_in,
                              void* d_out, int out_size, void* d_ws, size_t ws_size,
                              hipStream_t stream) {
  const float* x0 = (const float*)d_in[0];
  const float* x1 = (const float*)d_in[1];
  const float* qkv_w = (const float*)d_in[2];
  const float* qkv_b = (const float*)d_in[3];
  const float* proj_w = (const float*)d_in[4];
  const float* proj_b = (const float*)d_in[5];
  const float* rpb0_w1 = (const float*)d_in[6];
  const float* rpb0_b1 = (const float*)d_in[7];
  const float* rpb0_w2 = (const float*)d_in[8];
  const float* rpb0_b2 = (const float*)d_in[9];
  const float* rpb1_w1 = (const float*)d_in[10];
  const float* rpb1_b1 = (const float*)d_in[11];
  const float* rpb1_w2 = (const float*)d_in[12];
  const float* rpb1_b2 = (const float*)d_in[13];
  const float* coords0 = (const float*)d_in[14];
  const float* coords1 = (const float*)d_in[15];
  const int* idx0 = (const int*)d_in[16];
  const int* idx1 = (const int*)d_in[17];

  // q_win (fp32, windowed) lives in d_out (12,845,056 floats); attention
  // output overwrites it in place; k_proj is in-place on d_out.
  float* q_win = (float*)d_out;

  // workspace (bytes): 56.1 MB total
  char* ws = (char*)d_ws;
  bf16_t* k0 = (bf16_t*)(ws + 0);               // 25,690,112
  bf16_t* v0 = (bf16_t*)(ws + 25690112);        // 25,690,112
  bf16_t* k1 = (bf16_t*)(ws + 51380224);        //    524,288
  bf16_t* v1 = (bf16_t*)(ws + 51904512);        //    524,288
  float* rpb = (float*)(ws + 52428800);         //  6,422,528 -> end 58,851,328

  k_qkv<<<dim3(1600, 3), 256, 0, stream>>>(x0, x1, qkv_w, qkv_b,
                                           q_win, k0, v0, k1, v1);
  k_rpb<<<1568, 256, 0, stream>>>(coords0, coords1, rpb0_w1, rpb0_b1, rpb0_w2,
                                  rpb0_b2, rpb1_w1, rpb1_b1, rpb1_w2, rpb1_b2,
                                  rpb);
  k_attn<<<4096, 256, 0, stream>>>(q_win, k0, v0, k1, v1, idx0, idx1, rpb,
                                   q_win /* in-place attention output */);
  k_proj<<<1568, 256, 0, stream>>>(q_win, proj_w, proj_b, (float*)d_out);
}

// Round 4
// 228.347 us; speedup vs baseline: 1.2251x; 1.2251x over previous
//
#include <hip/hip_runtime.h>
#include <hip/hip_bf16.h>

// ---------------------------------------------------------------------------
// WindowAttention: B=32 RES=56 C=128 HEADS=4 HD=32 WS=7 NW=8 NQ=64 WA=49
// 128 keys/window (64 gathered full-res + 64 x1-level). fp32 I/O, bf16 MFMA.
// Buffer plan:
//   d_out: per-window interleaved — q (bf16, first 12544B of each 25088B
//   window slot) -> k_attn preloads Q to regs, then writes fp32 attention
//   output over the full slot (block-local alias) -> k_proj in-place.
//   d_ws 58.9MB: k0,v0,k1,v1 (bf16) + rpb (fp32, pre-scaled by sqrt(32),
//   padded 8KB for C-layout garbage-row reads).
// ---------------------------------------------------------------------------

typedef __bf16 bf16_t;
typedef __bf16 bf16x8 __attribute__((ext_vector_type(8)));
typedef float f32x4 __attribute__((ext_vector_type(4)));

static __device__ __forceinline__ f32x4 mfma_bf16(bf16x8 a, bf16x8 b, f32x4 c) {
  return __builtin_amdgcn_mfma_f32_16x16x32_bf16(a, b, c, 0, 0, 0);
}

static __device__ __forceinline__ bf16x8 cvt8(const float* __restrict__ p) {
  float4 a = *(const float4*)p;
  float4 b = *(const float4*)(p + 4);
  bf16x8 r;
  r[0] = (bf16_t)a.x; r[1] = (bf16_t)a.y; r[2] = (bf16_t)a.z; r[3] = (bf16_t)a.w;
  r[4] = (bf16_t)b.x; r[5] = (bf16_t)b.y; r[6] = (bf16_t)b.z; r[7] = (bf16_t)b.w;
  return r;
}

#define NB 32
#define RES 56
#define CH 128
#define NW 8
#define NQ 64
#define WA 49
#define X0_ROWS (NB * RES * RES)       // 100352
#define SCALE 0.17677669529663687f     // 32^-0.5
#define SQRT32 5.656854249492381f

// ---------------------------------------------------------------------------
// K1: qkv GEMM, A staged once, cb=q/k/v looped in-block. grid 1600 x 256.
// q -> bf16 block-interleaved in d_out; k/v -> bf16 k0/v0/k1/v1.
// ---------------------------------------------------------------------------
__global__ __launch_bounds__(256) void k_qkv(
    const float* __restrict__ x0, const float* __restrict__ x1,
    const float* __restrict__ w, const float* __restrict__ bias,
    bf16_t* __restrict__ qout,          // d_out, interleaved windows
    bf16_t* __restrict__ k0, bf16_t* __restrict__ v0,
    bf16_t* __restrict__ k1, bf16_t* __restrict__ v1) {
  __shared__ __align__(16) bf16_t Asm[64][136];
  __shared__ __align__(16) bf16_t Bsm[128][136];
  const int rb = blockIdx.x;           // 0..1599 (>=1568: x1 rows)
  const int tid = threadIdx.x;
  const size_t row0 = (size_t)rb * 64;
  const bool is_x0 = (rb < 1568);
  const int b_ = rb / 49;              // 3136 = 49*64: block never crosses batch
  const int pix0 = (rb - b_ * 49) * 64;
  const int i1base = (rb - 1568) * 64;

  const float* src = is_x0 ? (x0 + row0 * CH)
                           : (x1 + (row0 - X0_ROWS) * CH);
#pragma unroll
  for (int i = 0; i < 4; ++i) {        // A: 64x128
    int uid = tid + 256 * i;
    int r = uid >> 4, cs = uid & 15;
    *(bf16x8*)&Asm[r][cs * 8] = cvt8(src + (size_t)r * CH + cs * 8);
  }

  const int wid = tid >> 6, l = tid & 63;
  const int lr = l & 15, lkg = l >> 4, lk = lkg * 8;

  for (int cb = 0; cb < 3; ++cb) {
    const float* wsrc = w + (size_t)cb * 128 * CH;
#pragma unroll
    for (int i = 0; i < 8; ++i) {      // B: 128x128
      int uid = tid + 256 * i;
      int r = uid >> 4, cs = uid & 15;
      *(bf16x8*)&Bsm[r][cs * 8] = cvt8(wsrc + (size_t)r * CH + cs * 8);
    }
    __syncthreads();

    f32x4 zero = {0.f, 0.f, 0.f, 0.f};
    f32x4 acc[8];
#pragma unroll
    for (int nt = 0; nt < 8; ++nt) acc[nt] = zero;
#pragma unroll
    for (int ks = 0; ks < 4; ++ks) {
      bf16x8 a = *(const bf16x8*)&Asm[wid * 16 + lr][ks * 32 + lk];
#pragma unroll
      for (int nt = 0; nt < 8; ++nt) {
        bf16x8 b = *(const bf16x8*)&Bsm[nt * 16 + lr][ks * 32 + lk];
        acc[nt] = mfma_bf16(a, b, acc[nt]);
      }
    }
    float bias_v[8];
#pragma unroll
    for (int nt = 0; nt < 8; ++nt) bias_v[nt] = bias[cb * 128 + nt * 16 + lr];

#pragma unroll
    for (int r4 = 0; r4 < 4; ++r4) {
      int local = wid * 16 + lkg * 4 + r4;
      if (is_x0) {
        int pix = pix0 + local;
        int rr = pix / 56, cc = pix - rr * 56;
        if (cb == 0) {
          int wn = b_ * 64 + (rr / 7) * 8 + cc / 7;
          int nidx = (rr % 7) * 7 + (cc % 7);
          bf16_t* dst = qout + (size_t)wn * 12544 + nidx * 128;
#pragma unroll
          for (int nt = 0; nt < 8; ++nt)
            dst[nt * 16 + lr] = (bf16_t)(acc[nt][r4] + bias_v[nt]);
        } else {
          bf16_t* dst = (cb == 1 ? k0 : v0) +
                        ((size_t)b_ * 3136 + pix) * CH;
#pragma unroll
          for (int nt = 0; nt < 8; ++nt)
            dst[nt * 16 + lr] = (bf16_t)(acc[nt][r4] + bias_v[nt]);
        }
      } else if (cb != 0) {
        bf16_t* dst = (cb == 1 ? k1 : v1) + (size_t)(i1base + local) * CH;
#pragma unroll
        for (int nt = 0; nt < 8; ++nt)
          dst[nt * 16 + lr] = (bf16_t)(acc[nt][r4] + bias_v[nt]);
      }
    }
    __syncthreads();                   // before restaging Bsm
  }
}

// ---------------------------------------------------------------------------
// K2: rpb MLP -> rpb_s = rpb * sqrt(32)  (pre-scaled so k_attn can fold the
// 1/sqrt(HD) score scale into exp). fp32, layout [(q*4+h)*49+n][m].
// ---------------------------------------------------------------------------
__global__ __launch_bounds__(256) void k_rpb(
    const float* __restrict__ c0, const float* __restrict__ c1,
    const float* __restrict__ w10, const float* __restrict__ b10,
    const float* __restrict__ w20, const float* __restrict__ b20,
    const float* __restrict__ w11, const float* __restrict__ b11,
    const float* __restrict__ w21, const float* __restrict__ b21,
    float* __restrict__ rpb) {
  __shared__ float w1s[2][32][2], b1s[2][32], w2s[2][4][32], b2s[2][4];
  const int tid = threadIdx.x;
  if (tid < 64) {
    int s = tid >> 5, j = tid & 31;
    const float* w1p = s ? w11 : w10;
    const float* b1p = s ? b11 : b10;
    w1s[s][j][0] = w1p[j * 2];
    w1s[s][j][1] = w1p[j * 2 + 1];
    b1s[s][j] = b1p[j];
  }
  {
    int s = tid >> 7, rem = tid & 127, h = rem >> 5, j = rem & 31;
    w2s[s][h][j] = s ? w21[h * 32 + j] : w20[h * 32 + j];
  }
  if (tid < 8) {
    int s = tid >> 2, h = tid & 3;
    b2s[s][h] = s ? b21[h] : b20[h];
  }
  __syncthreads();

  int L = blockIdx.x * 256 + tid;      // < 64*49*128
  int m = L & 127;
  int n = (L >> 7) % WA;
  int qi = L / (128 * WA);
  int s = m >> 6, mi = m & 63;
  const float* cp = (s ? c1 : c0) + (((size_t)qi * WA + n) * 64 + mi) * 2;
  float cx = cp[0], cy = cp[1];
  float a0 = 0.f, a1 = 0.f, a2 = 0.f, a3 = 0.f;
#pragma unroll
  for (int j = 0; j < 32; ++j) {
    float h = fmaxf(w1s[s][j][0] * cx + w1s[s][j][1] * cy + b1s[s][j], 0.f);
    a0 += w2s[s][0][j] * h;
    a1 += w2s[s][1][j] * h;
    a2 += w2s[s][2][j] * h;
    a3 += w2s[s][3][j] * h;
  }
  size_t base = ((size_t)qi * 4 * WA + n) * 128 + m;
  rpb[base] = (a0 + b2s[s][0]) * SQRT32;
  rpb[base + (size_t)WA * 128] = (a1 + b2s[s][1]) * SQRT32;
  rpb[base + (size_t)2 * WA * 128] = (a2 + b2s[s][2]) * SQRT32;
  rpb[base + (size_t)3 * WA * 128] = (a3 + b2s[s][3]) * SQRT32;
}

// ---------------------------------------------------------------------------
// K3: attention. block = (b, qi, head-pair hp). 256 thr. ONE barrier.
// acc init = rpb_s (C-layout); in-register softmax (shfl over 16 lanes);
// per-wave private Sm rows => no barriers after gather.
// Q preloaded (both heads) before barrier; fp32 output overwrites the
// window slot in d_out (block-local alias with the bf16 q).
// ---------------------------------------------------------------------------
__global__ __launch_bounds__(256) void k_attn(
    const bf16_t* qin,                  // d_out interleaved, aliased
    const bf16_t* __restrict__ k0, const bf16_t* __restrict__ v0,
    const bf16_t* __restrict__ k1, const bf16_t* __restrict__ v1,
    const int* __restrict__ idx0, const int* __restrict__ idx1,
    const float* __restrict__ rpb,
    float* attn_out) {                  // d_out, aliased
  __shared__ __align__(16) bf16_t Kt[128][72];   // [key][ch-in-pair]
  __shared__ __align__(16) bf16_t Vt[64][136];   // [ch-in-pair][key]
  __shared__ __align__(16) bf16_t Sm[64][136];   // P, per-wave 16-row slices

  const int bid = blockIdx.x;          // 4096 = 32*64*2
  const int hp = bid & 1;
  const int qi = (bid >> 1) & 63;
  const int b = bid >> 7;
  const int tid = threadIdx.x;
  const int wn = b * 64 + qi;

  // ---- gather: key = lane-fastest => Vt scatter is 2-way (free)
#pragma unroll
  for (int i = 0; i < 4; ++i) {
    int uid = tid + 256 * i;           // 0..1023
    int key = uid & 127, seg = uid >> 7;
    size_t srcrow;
    const bf16_t *kbase, *vbase;
    if (key < 64) {
      srcrow = (size_t)b * 3136 + idx0[qi * 64 + key];
      kbase = k0; vbase = v0;
    } else {
      srcrow = (size_t)b * 64 + idx1[qi * 64 + key - 64];
      kbase = k1; vbase = v1;
    }
    size_t off = srcrow * CH + hp * 64 + seg * 8;
    *(uint4*)&Kt[key][seg * 8] = *(const uint4*)(kbase + off);
    union { uint4 u; bf16_t h[8]; } cv;
    cv.u = *(const uint4*)(vbase + off);
#pragma unroll
    for (int e = 0; e < 8; ++e) Vt[seg * 8 + e][key] = cv.h[e];
  }

  const int wid = tid >> 6, l = tid & 63;
  const int lr = l & 15, lkg = l >> 4, lk = lkg * 8;
  int qr = wid * 16 + lr;
  if (qr > WA - 1) qr = WA - 1;

  // ---- preload BOTH heads' Q fragments before the barrier (alias safety)
  const bf16_t* qb = qin + (size_t)wn * 12544;
  bf16x8 qf[2];
  qf[0] = *(const bf16x8*)&qb[qr * 128 + hp * 64 + lk];
  qf[1] = *(const bf16x8*)&qb[qr * 128 + hp * 64 + 32 + lk];
  __syncthreads();                     // the only barrier

  const int myrow = wid * 16 + lkg * 4;     // + r4
  float* obase = attn_out + (size_t)wn * 6272;

#pragma unroll
  for (int lh = 0; lh < 2; ++lh) {
    const int hh = hp * 2 + lh;
    // ---- acc init = pre-scaled rpb in C-layout
    const float* rp = rpb + ((size_t)(qi * 4 + hh) * WA) * 128;
    f32x4 acc[8];
#pragma unroll
    for (int nt = 0; nt < 8; ++nt) {
#pragma unroll
      for (int r4 = 0; r4 < 4; ++r4)
        acc[nt][r4] = rp[(myrow + r4) * 128 + nt * 16 + lr];
    }
    // ---- QK^T
#pragma unroll
    for (int nt = 0; nt < 8; ++nt) {
      bf16x8 bfr = *(const bf16x8*)&Kt[nt * 16 + lr][lh * 32 + lk];
      acc[nt] = mfma_bf16(qf[lh], bfr, acc[nt]);
    }
    // ---- in-register softmax (rows live in fixed lanes)
    float mx[4] = {-1e30f, -1e30f, -1e30f, -1e30f};
#pragma unroll
    for (int nt = 0; nt < 8; ++nt)
#pragma unroll
      for (int r4 = 0; r4 < 4; ++r4) mx[r4] = fmaxf(mx[r4], acc[nt][r4]);
#pragma unroll
    for (int m = 1; m < 16; m <<= 1)
#pragma unroll
      for (int r4 = 0; r4 < 4; ++r4)
        mx[r4] = fmaxf(mx[r4], __shfl_xor(mx[r4], m));
    float sum[4] = {0.f, 0.f, 0.f, 0.f};
#pragma unroll
    for (int nt = 0; nt < 8; ++nt)
#pragma unroll
      for (int r4 = 0; r4 < 4; ++r4) {
        float p = __expf(SCALE * (acc[nt][r4] - mx[r4]));
        acc[nt][r4] = p;
        sum[r4] += p;
      }
#pragma unroll
    for (int m = 1; m < 16; m <<= 1)
#pragma unroll
      for (int r4 = 0; r4 < 4; ++r4) sum[r4] += __shfl_xor(sum[r4], m);
    // ---- P -> Sm (own rows only; 2-way conflicts = free)
#pragma unroll
    for (int nt = 0; nt < 8; ++nt)
#pragma unroll
      for (int r4 = 0; r4 < 4; ++r4)
        Sm[myrow + r4][nt * 16 + lr] = (bf16_t)acc[nt][r4];
    // no barrier: Sm rows wid*16..+15 written & read by this wave only
    f32x4 zero = {0.f, 0.f, 0.f, 0.f};
    f32x4 oacc[2];
    oacc[0] = zero; oacc[1] = zero;
#pragma unroll
    for (int ks = 0; ks < 4; ++ks) {
      bf16x8 pa = *(const bf16x8*)&Sm[wid * 16 + lr][ks * 32 + lk];
#pragma unroll
      for (int nt2 = 0; nt2 < 2; ++nt2) {
        bf16x8 vb = *(const bf16x8*)&Vt[lh * 32 + nt2 * 16 + lr][ks * 32 + lk];
        oacc[nt2] = mfma_bf16(pa, vb, oacc[nt2]);
      }
    }
#pragma unroll
    for (int nt2 = 0; nt2 < 2; ++nt2)
#pragma unroll
      for (int r4 = 0; r4 < 4; ++r4) {
        int rown = myrow + r4;
        if (rown < WA)
          obase[rown * 128 + hh * 32 + nt2 * 16 + lr] = oacc[nt2][r4] / sum[r4];
      }
  }
}

// ---------------------------------------------------------------------------
// K4: out = attn @ proj_w.T + proj_b, in place on d_out. grid 1568 x 256.
// ---------------------------------------------------------------------------
__global__ __launch_bounds__(256) void k_proj(
    const float* attn,                  // aliases out
    const float* __restrict__ pw, const float* __restrict__ pb,
    float* out) {
  __shared__ __align__(16) bf16_t Asm[64][136];
  __shared__ __align__(16) bf16_t Bsm[128][136];
  const int rb = blockIdx.x;
  const int tid = threadIdx.x;
  const size_t row0 = (size_t)rb * 64;
#pragma unroll
  for (int i = 0; i < 4; ++i) {
    int uid = tid + 256 * i;
    int r = uid >> 4, cs = uid & 15;
    *(bf16x8*)&Asm[r][cs * 8] = cvt8(attn + (row0 + r) * CH + cs * 8);
  }
#pragma unroll
  for (int i = 0; i < 8; ++i) {
    int uid = tid + 256 * i;
    int r = uid >> 4, cs = uid & 15;
    *(bf16x8*)&Bsm[r][cs * 8] = cvt8(pw + (size_t)r * CH + cs * 8);
  }
  __syncthreads();

  const int wid = tid >> 6, l = tid & 63;
  const int lr = l & 15, lkg = l >> 4, lk = lkg * 8;
  f32x4 zero = {0.f, 0.f, 0.f, 0.f};
  f32x4 acc[8];
#pragma unroll
  for (int nt = 0; nt < 8; ++nt) acc[nt] = zero;
#pragma unroll
  for (int ks = 0; ks < 4; ++ks) {
    bf16x8 a = *(const bf16x8*)&Asm[wid * 16 + lr][ks * 32 + lk];
#pragma unroll
    for (int nt = 0; nt < 8; ++nt) {
      bf16x8 b = *(const bf16x8*)&Bsm[nt * 16 + lr][ks * 32 + lk];
      acc[nt] = mfma_bf16(a, b, acc[nt]);
    }
  }
#pragma unroll
  for (int nt = 0; nt < 8; ++nt) {
    int n = nt * 16 + lr;
    float bs = pb[n];
#pragma unroll
    for (int r4 = 0; r4 < 4; ++r4) {
      size_t g = row0 + (size_t)(wid * 16 + lkg * 4 + r4);
      out[g * CH + n] = acc[nt][r4] + bs;
    }
  }
}

// ---------------------------------------------------------------------------
// launch
// ---------------------------------------------------------------------------
extern "C" void kernel_launch(void* const* d_in, const int* in_sizes, int n_in,
                              void* d_out, int out_size, void* d_ws, size_t ws_size,
                              hipStream_t stream) {
  const float* x0 = (const float*)d_in[0];
  const float* x1 = (const float*)d_in[1];
  const float* qkv_w = (const float*)d_in[2];
  const float* qkv_b = (const float*)d_in[3];
  const float* proj_w = (const float*)d_in[4];
  const float* proj_b = (const float*)d_in[5];
  const float* rpb0_w1 = (const float*)d_in[6];
  const float* rpb0_b1 = (const float*)d_in[7];
  const float* rpb0_w2 = (const float*)d_in[8];
  const float* rpb0_b2 = (const float*)d_in[9];
  const float* rpb1_w1 = (const float*)d_in[10];
  const float* rpb1_b1 = (const float*)d_in[11];
  const float* rpb1_w2 = (const float*)d_in[12];
  const float* rpb1_b2 = (const float*)d_in[13];
  const float* coords0 = (const float*)d_in[14];
  const float* coords1 = (const float*)d_in[15];
  const int* idx0 = (const int*)d_in[16];
  const int* idx1 = (const int*)d_in[17];

  // workspace: 58.86 MB (rpb padded 8KB for C-layout garbage-row reads)
  char* ws = (char*)d_ws;
  bf16_t* k0 = (bf16_t*)(ws + 0);               // 25,690,112
  bf16_t* v0 = (bf16_t*)(ws + 25690112);        // 25,690,112
  bf16_t* k1 = (bf16_t*)(ws + 51380224);        //    524,288
  bf16_t* v1 = (bf16_t*)(ws + 51904512);        //    524,288
  float* rpb = (float*)(ws + 52428800);         //  6,422,528 + 8,192 pad

  k_qkv<<<1600, 256, 0, stream>>>(x0, x1, qkv_w, qkv_b,
                                  (bf16_t*)d_out, k0, v0, k1, v1);
  k_rpb<<<1568, 256, 0, stream>>>(coords0, coords1, rpb0_w1, rpb0_b1, rpb0_w2,
                                  rpb0_b2, rpb1_w1, rpb1_b1, rpb1_w2, rpb1_b2,
                                  rpb);
  k_attn<<<4096, 256, 0, stream>>>((const bf16_t*)d_out, k0, v0, k1, v1,
                                   idx0, idx1, rpb, (float*)d_out);
  k_proj<<<1568, 256, 0, stream>>>((const float*)d_out, proj_w, proj_b,
                                   (float*)d_out);
}